// Round 2
// baseline (335.184 us; speedup 1.0000x reference)
//
#include <hip/hip_runtime.h>

#define LAMBDA_COOR 5.0f
#define LAMBDA_NOOBJ 0.5f

constexpr int TPB = 256;
constexpr int WAVES_PER_BLOCK = TPB / 64;     // 4
constexpr int WAVE_F4 = 5 * 64;               // 320 float4 per wave tile
constexpr int WAVE_FLOATS = WAVE_F4 * 4;      // 1280 floats = 256 cells

// Per-wave LDS staging: coalesced global float4 loads -> LDS -> per-lane
// 4-cell (20-float) compute. No block barriers needed in the main loop
// (intra-wave LDS dependences are ordered by lgkmcnt).
__global__ __launch_bounds__(TPB) void yolo_loss_kernel(
    const float4* __restrict__ outp4, const float4* __restrict__ tgt4,
    float* __restrict__ loss, int n_wtiles, float inv_b)
{
    __shared__ float so[WAVES_PER_BLOCK][WAVE_FLOATS];
    __shared__ float st[WAVES_PER_BLOCK][WAVE_FLOATS];

    const int lane  = threadIdx.x & 63;
    const int wid   = threadIdx.x >> 6;
    const int gwave = blockIdx.x * WAVES_PER_BLOCK + wid;
    const int nwaves = gridDim.x * WAVES_PER_BLOCK;

    float acc = 0.0f;

    for (int w = gwave; w < n_wtiles; w += nwaves) {
        const size_t base4 = (size_t)w * WAVE_F4;

        // Coalesced loads: lane stride 16 B per instruction.
        float4 vo[5], vt[5];
        #pragma unroll
        for (int k = 0; k < 5; ++k) {
            vo[k] = outp4[base4 + (size_t)(k * 64 + lane)];
            vt[k] = tgt4 [base4 + (size_t)(k * 64 + lane)];
        }

        float4* so4 = (float4*)so[wid];
        float4* st4 = (float4*)st[wid];
        #pragma unroll
        for (int k = 0; k < 5; ++k) {
            so4[k * 64 + lane] = vo[k];
            st4[k * 64 + lane] = vt[k];
        }

        // Each lane: 4 cells = floats [20*lane .. 20*lane+19] of this tile.
        const float* o = &so[wid][20 * lane];
        const float* t = &st[wid][20 * lane];
        #pragma unroll
        for (int c = 0; c < 4; ++c) {
            const float* oc = o + 5 * c;
            const float* tc = t + 5 * c;
            float conf = oc[0];
            float coord = 0.0f;
            #pragma unroll
            for (int k = 1; k < 5; ++k) {
                float d = oc[k] - tc[k];
                coord = fmaf(d, d, coord);
            }
            float obj   = fmaf(LAMBDA_COOR, coord, (conf - 1.0f) * (conf - 1.0f));
            float noobj = LAMBDA_NOOBJ * conf * conf;
            acc += (tc[0] > 0.0f) ? obj : noobj;
        }
    }

    // Wave reduction (64 lanes)
    #pragma unroll
    for (int off = 32; off > 0; off >>= 1)
        acc += __shfl_down(acc, off, 64);

    __shared__ float wave_sums[WAVES_PER_BLOCK];
    if (lane == 0) wave_sums[wid] = acc;
    __syncthreads();

    if (threadIdx.x == 0) {
        float s = 0.0f;
        #pragma unroll
        for (int i = 0; i < WAVES_PER_BLOCK; ++i) s += wave_sums[i];
        atomicAdd(loss, s * inv_b);
    }
}

extern "C" void kernel_launch(void* const* d_in, const int* in_sizes, int n_in,
                              void* d_out, int out_size, void* d_ws, size_t ws_size,
                              hipStream_t stream) {
    const float4* outputs = (const float4*)d_in[0];
    const float4* targets = (const float4*)d_in[1];
    float* loss = (float*)d_out;

    const int n_elems  = in_sizes[0];                 // 41,943,040
    const int n_wtiles = n_elems / WAVE_FLOATS;       // 32,768 wave tiles
    const float inv_b  = 1.0f / 128.0f;               // B = 128

    // d_out is poisoned to 0xAA before every timed launch; zero it on-stream.
    hipMemsetAsync(d_out, 0, sizeof(float), stream);

    const int blocks = 2048;                          // 8192 waves, 4 tiles/wave
    yolo_loss_kernel<<<blocks, TPB, 0, stream>>>(
        outputs, targets, loss, n_wtiles, inv_b);
}